// Round 1
// baseline (133.782 us; speedup 1.0000x reference)
//
#include <hip/hip_runtime.h>
#include <cstddef>

// out[b,d,p] = sum_{t=0..62} filt[t] * act[b, (d+31-t) & 511, p]
// (circulant Toeplitz from the reference reduces to a 63-tap circular
//  conv along channels; derived from pad_left=224, roll=257.)

#define NB     32
#define NC     512
#define HW     3136          // 56*56
#define HWT    32            // hw positions per block
#define NTILE  (HW / HWT)    // 98
#define TAPS   63
#define RCH    16            // output channels per thread per phase
#define NPHASE 4             // 4*16 = 64 channels per thread = 512 per block
#define TPB    256

__device__ __forceinline__ void gload_lds16(const float* g, float* l) {
    __builtin_amdgcn_global_load_lds(
        (const __attribute__((address_space(1))) void*)g,
        (__attribute__((address_space(3))) void*)l,
        16, 0, 0);
}

__global__ __launch_bounds__(TPB, 2)
void toeplitz_inhib_kernel(const float* __restrict__ act,
                           const float* __restrict__ filt,
                           float* __restrict__ out) {
    // all 512 channel rows x 32 floats for this (b, hw-tile): 64 KB
    __shared__ __align__(16) float lds[NC * HWT];

    const int tid  = threadIdx.x;
    const int bx   = blockIdx.x;
    const int b    = bx / NTILE;
    const int tile = bx - b * NTILE;
    const int hw0  = tile * HWT;

    // ---- stage: 512 rows x 128 B, via global_load_lds width=16.
    // One issue = 64 lanes x 16 B = 1024 B = 8 rows. 16 issues per wave.
    {
        const int wave = tid >> 6;          // 0..3
        const int lane = tid & 63;
        const float* gb = act + (size_t)b * NC * HW + hw0;
        #pragma unroll
        for (int i = 0; i < 16; ++i) {
            const int row8 = wave * 128 + i * 8;                    // wave-uniform
            const float* src = gb + (size_t)(row8 + (lane >> 3)) * HW
                                  + (lane & 7) * 4;
            gload_lds16(src, &lds[row8 * HWT]);
        }
    }
    __syncthreads();   // compiler emits vmcnt(0) drain before barrier

    const int hw_l = tid & 31;   // hw position within tile
    const int cg   = tid >> 5;   // 0..7: channel super-group

    for (int ph = 0; ph < NPHASE; ++ph) {
        const int d0 = cg * 64 + ph * RCH;   // first output channel of this thread
        float acc[RCH];
        float W[RCH];
        #pragma unroll
        for (int r = 0; r < RCH; ++r) acc[r] = 0.0f;
        // window W[r] = X[r+s] where X[q] = lds[(d0-31+q) & 511][hw_l]
        #pragma unroll
        for (int r = 0; r < RCH; ++r)
            W[r] = lds[(((d0 - 31 + r) & (NC - 1)) << 5) + hw_l];

        #pragma unroll
        for (int s = 0; s < TAPS; ++s) {
            const float wt = filt[62 - s];   // uniform -> s_load, scalar cache
            #pragma unroll
            for (int r = 0; r < RCH; ++r) acc[r] = fmaf(wt, W[r], acc[r]);
            if (s < TAPS - 1) {
                #pragma unroll
                for (int r = 0; r < RCH - 1; ++r) W[r] = W[r + 1];  // rename, no movs
                W[RCH - 1] = lds[(((d0 - 31 + RCH + s) & (NC - 1)) << 5) + hw_l];
            }
        }

        float* ob = out + ((size_t)b * NC + d0) * HW + hw0 + hw_l;
        #pragma unroll
        for (int r = 0; r < RCH; ++r)
            ob[(size_t)r * HW] = acc[r];
    }
}

extern "C" void kernel_launch(void* const* d_in, const int* in_sizes, int n_in,
                              void* d_out, int out_size, void* d_ws, size_t ws_size,
                              hipStream_t stream) {
    const float* act  = (const float*)d_in[0];   // (32, 512, 56, 56) f32
    const float* filt = (const float*)d_in[1];   // (1, 1, 63) f32
    float* out = (float*)d_out;                  // (32, 512, 56, 56) f32
    dim3 grid(NB * NTILE);   // 3136 blocks
    dim3 block(TPB);
    hipLaunchKernelGGL(toeplitz_inhib_kernel, grid, block, 0, stream,
                       act, filt, out);
}

// Round 2
// 86.345 us; speedup vs baseline: 1.5494x; 1.5494x over previous
//
#include <hip/hip_runtime.h>
#include <hip/hip_bf16.h>
#include <cstddef>

// out[b,d,p] = sum_{t=0..62} filt[t] * act[b, (d+31-t) & 511, p]
// Banded circulant as bf16 MFMA GEMM: per 16-row d-tile, exactly 3 aligned
// 32-wide c-blocks are nonzero. A-fragments (6 distinct, by d0-c0 offset)
// built from the filter; x staged in LDS as bf16 [hw][c] (XOR-swizzled).

#define NC    512
#define HW    3136          // 56*56
#define NT    32            // hw positions per block
#define NTILE (HW / NT)     // 98
#define NB    32
#define TPB   256

typedef __attribute__((ext_vector_type(8))) short bf16x8;
typedef __attribute__((ext_vector_type(4))) float f32x4;

__device__ __forceinline__ short f2bf(float f) {
    union { __hip_bfloat16 h; short s; } u;
    u.h = __float2bfloat16(f);
    return u.s;
}

__global__ __launch_bounds__(TPB, 5)
void toeplitz_mfma_kernel(const float* __restrict__ act,
                          const float* __restrict__ filt,
                          float* __restrict__ out) {
    // bf16 x-tile, layout [hw][c], byte addr = hw*1024 + ((c*2) ^ ((hw&7)<<4))
    __shared__ __align__(16) unsigned short xs[NT * NC];   // 32 KB

    const int tid  = threadIdx.x;
    const int wv   = tid >> 6;          // wave 0..3
    const int ln   = tid & 63;
    const int bx   = blockIdx.x;
    const int b    = bx / NTILE;
    const int tile = bx - b * NTILE;
    const int hw0  = tile * NT;

    // ---- A fragments: A_delta[r,k] = filt[delta+31+r-k] (0 elsewhere)
    // lane: r = ln&15, k = (ln>>4)*8 + i.  deltas: par0 {32,0,-32}, par1 {48,16,-16}
    const int r_a = ln & 15;
    const int k0  = (ln >> 4) * 8;
    bf16x8 af0, af1, af2, af3, af4, af5;
    #pragma unroll
    for (int i = 0; i < 8; ++i) {
        const int base = 31 + r_a - (k0 + i);
        int t;
        t = base + 32; af0[i] = (t >= 0 && t < 63) ? f2bf(filt[t]) : (short)0;
        t = base;      af1[i] = (t >= 0 && t < 63) ? f2bf(filt[t]) : (short)0;
        t = base - 32; af2[i] = (t >= 0 && t < 63) ? f2bf(filt[t]) : (short)0;
        t = base + 48; af3[i] = (t >= 0 && t < 63) ? f2bf(filt[t]) : (short)0;
        t = base + 16; af4[i] = (t >= 0 && t < 63) ? f2bf(filt[t]) : (short)0;
        t = base - 16; af5[i] = (t >= 0 && t < 63) ? f2bf(filt[t]) : (short)0;
    }

    // ---- stage x[b][:, hw0:hw0+32] -> LDS bf16 [hw][c], transposing.
    // Coalesced: per instr, 8 rows x 128 B contiguous. Pair rows (c, c+1)
    // in one thread so LDS writes are b32.
    {
        const float* gb = act + (size_t)b * NC * HW + hw0;
        const int g = ln >> 3;      // 0..7 row-group
        const int q = ln & 7;       // hw quad
        #pragma unroll
        for (int j = 0; j < 8; ++j) {
            const int r0 = wv * 128 + j * 16 + 2 * g;   // even row
            const f32x4 a0 = *reinterpret_cast<const f32x4*>(gb + (size_t)r0 * HW + 4 * q);
            const f32x4 a1 = *reinterpret_cast<const f32x4*>(gb + (size_t)(r0 + 1) * HW + 4 * q);
            #pragma unroll
            for (int t4 = 0; t4 < 4; ++t4) {
                const int hw = 4 * q + t4;
                const unsigned int pk = (unsigned int)(unsigned short)f2bf(a0[t4])
                                      | ((unsigned int)(unsigned short)f2bf(a1[t4]) << 16);
                const int byte = hw * (NC * 2) + ((r0 * 2) ^ ((hw & 7) << 4));
                *reinterpret_cast<unsigned int*>(reinterpret_cast<char*>(xs) + byte) = pk;
            }
        }
    }
    __syncthreads();

    // ---- banded MFMA. wave -> d-half = wv>>1 (256 ch), hw-half = wv&1 (16 cols)
    const int col0  = (wv & 1) * 16;
    const int dbase = (wv >> 1) * 256;
    const int hwl   = col0 + (ln & 15);
    const int rowbyte = hwl * (NC * 2);
    const int swz     = (hwl & 7) << 4;
    const int kbyte0  = k0 * 2;

    float* ob = out + (size_t)b * NC * HW + hw0 + hwl;
    const int orow = (ln >> 4) * 4;

    #define BFRAG(c0) (*reinterpret_cast<const bf16x8*>(                      \
        reinterpret_cast<const char*>(xs) +                                   \
        (rowbyte + ((((c0) & (NC - 1)) * 2 + kbyte0) ^ swz))))

    #pragma unroll 2
    for (int dt2 = 0; dt2 < 8; ++dt2) {
        const int d0 = dbase + dt2 * 32;        // d0 % 32 == 0
        {
            f32x4 acc = {0.f, 0.f, 0.f, 0.f};
            acc = __builtin_amdgcn_mfma_f32_16x16x32_bf16(af0, BFRAG(d0 - 32), acc, 0, 0, 0);
            acc = __builtin_amdgcn_mfma_f32_16x16x32_bf16(af1, BFRAG(d0     ), acc, 0, 0, 0);
            acc = __builtin_amdgcn_mfma_f32_16x16x32_bf16(af2, BFRAG(d0 + 32), acc, 0, 0, 0);
            #pragma unroll
            for (int r = 0; r < 4; ++r)
                __builtin_nontemporal_store(acc[r], ob + (size_t)(d0 + orow + r) * HW);
        }
        {
            const int d1 = d0 + 16;             // d1 % 32 == 16
            f32x4 acc = {0.f, 0.f, 0.f, 0.f};
            acc = __builtin_amdgcn_mfma_f32_16x16x32_bf16(af3, BFRAG(d1 - 48), acc, 0, 0, 0);
            acc = __builtin_amdgcn_mfma_f32_16x16x32_bf16(af4, BFRAG(d1 - 16), acc, 0, 0, 0);
            acc = __builtin_amdgcn_mfma_f32_16x16x32_bf16(af5, BFRAG(d1 + 16), acc, 0, 0, 0);
            #pragma unroll
            for (int r = 0; r < 4; ++r)
                __builtin_nontemporal_store(acc[r], ob + (size_t)(d1 + orow + r) * HW);
        }
    }
    #undef BFRAG
}

extern "C" void kernel_launch(void* const* d_in, const int* in_sizes, int n_in,
                              void* d_out, int out_size, void* d_ws, size_t ws_size,
                              hipStream_t stream) {
    const float* act  = (const float*)d_in[0];   // (32, 512, 56, 56) f32
    const float* filt = (const float*)d_in[1];   // (1, 1, 63) f32
    float* out = (float*)d_out;                  // (32, 512, 56, 56) f32
    dim3 grid(NB * NTILE);    // 3136
    dim3 block(TPB);
    hipLaunchKernelGGL(toeplitz_mfma_kernel, grid, block, 0, stream,
                       act, filt, out);
}

// Round 3
// 68.814 us; speedup vs baseline: 1.9441x; 1.2548x over previous
//
#include <hip/hip_runtime.h>
#include <hip/hip_bf16.h>
#include <cstddef>

// out[b,d,p] = sum_{t=0..62} filt[t] * act[b, (d+31-t) & 511, p]
// Banded circulant via mfma_f32_32x32x16_bf16: per 32-row d-tile, 6 aligned
// K=16 c-blocks cover the band. C/D layout col=lane&31 -> full 128B-line
// stores. x staged in LDS bf16 [hw][c], swz(hw)=(((hw&7)^(hw>>3))<<4).

#define NC    512
#define HW    3136          // 56*56
#define NT    32            // hw positions per block
#define NTILE (HW / NT)     // 98
#define NB    32
#define TPB   256

typedef __attribute__((ext_vector_type(8)))  short bf16x8;
typedef __attribute__((ext_vector_type(4)))  float f32x4;
typedef __attribute__((ext_vector_type(16))) float f32x16;

__device__ __forceinline__ short f2bf(float f) {
    union { __hip_bfloat16 h; short s; } u;
    u.h = __float2bfloat16(f);
    return u.s;
}

__device__ __forceinline__ int swzf(int hw) {
    return (((hw & 7) ^ (hw >> 3)) << 4);
}

__global__ __launch_bounds__(TPB, 4)
void toeplitz_mfma32_kernel(const float* __restrict__ act,
                            const float* __restrict__ filt,
                            float* __restrict__ out) {
    // bf16 x-tile [hw][c]: byte = hw*1024 + ((c*2) ^ swzf(hw)).  32 KB.
    __shared__ __align__(16) unsigned short xs[NT * NC];

    const int tid  = threadIdx.x;
    const int wv   = tid >> 6;          // wave 0..3
    const int ln   = tid & 63;
    const int bx   = blockIdx.x;
    const int b    = bx / NTILE;
    const int tile = bx - b * NTILE;
    const int hw0  = tile * NT;

    // ---- A fragments: A_delta[r,k] = filt[delta + 31 + r - k] (0 outside)
    // lane: r = ln&31, k = (ln>>5)*8 + i.  delta(m) = 32 - 16*m, m=0..5
    const int r_a = ln & 31;
    const int k0  = (ln >> 5) * 8;
    bf16x8 af[6];
    #pragma unroll
    for (int m = 0; m < 6; ++m) {
        const int delta = 32 - 16 * m;
        #pragma unroll
        for (int i = 0; i < 8; ++i) {
            const int t = delta + 31 + r_a - (k0 + i);
            af[m][i] = (t >= 0 && t < 63) ? f2bf(filt[t]) : (short)0;
        }
    }

    // ---- stage x[b][:, hw0:hw0+32] -> LDS bf16 [hw][c] (transpose).
    // Per instr: 8 rows x 128 B contiguous global; paired rows -> b32 writes.
    {
        const float* gb = act + (size_t)b * NC * HW + hw0;
        const int g = ln >> 3;      // 0..7 row-pair group
        const int q = ln & 7;       // hw quad
        #pragma unroll
        for (int j = 0; j < 8; ++j) {
            const int r0 = wv * 128 + j * 16 + 2 * g;   // even row
            const f32x4 a0 = *reinterpret_cast<const f32x4*>(gb + (size_t)r0 * HW + 4 * q);
            const f32x4 a1 = *reinterpret_cast<const f32x4*>(gb + (size_t)(r0 + 1) * HW + 4 * q);
            #pragma unroll
            for (int t4 = 0; t4 < 4; ++t4) {
                const int hw = 4 * q + t4;
                const unsigned int pk = (unsigned int)(unsigned short)f2bf(a0[t4])
                                      | ((unsigned int)(unsigned short)f2bf(a1[t4]) << 16);
                const int byte = hw * (NC * 2) + ((r0 * 2) ^ swzf(hw));
                *reinterpret_cast<unsigned int*>(reinterpret_cast<char*>(xs) + byte) = pk;
            }
        }
    }
    __syncthreads();

    // ---- compute: wave wv owns d-tiles d0 = wv*128 + j*32, j=0..3.
    // B-frag for c-block c0: lane col = ln&31 (hw), k = (ln>>5)*8+i.
    const int hwl  = ln & 31;
    const int rowbyte = hwl * (NC * 2);
    const int swzv    = swzf(hwl);
    const int kb      = (ln >> 5) * 16;   // byte offset of k-half

    #define BFRAG(c0) (*reinterpret_cast<const bf16x8*>(                      \
        reinterpret_cast<const char*>(xs) +                                   \
        (rowbyte + (((((c0) & (NC - 1)) * 2) + kb) ^ swzv))))

    // 12 c-blocks per wave: c0 = wv*128 - 32 + 16*i, i=0..11 (each reused 3x)
    bf16x8 w[12];
    {
        const int cbase = wv * 128 - 32;
        #pragma unroll
        for (int i = 0; i < 12; ++i)
            w[i] = BFRAG(cbase + 16 * i);
    }

    float* ob = out + (size_t)b * NC * HW + hw0 + hwl;
    const int rhalf = (ln >> 5) * 4;

    #pragma unroll
    for (int j = 0; j < 4; ++j) {
        const int d0 = wv * 128 + j * 32;
        f32x16 acc;
        #pragma unroll
        for (int r = 0; r < 16; ++r) acc[r] = 0.0f;
        #pragma unroll
        for (int m = 0; m < 6; ++m)     // c0 = d0-32+16m, delta = 32-16m
            acc = __builtin_amdgcn_mfma_f32_32x32x16_bf16(af[m], w[2 * j + m], acc, 0, 0, 0);
        #pragma unroll
        for (int r = 0; r < 16; ++r) {
            const int row = d0 + (r & 3) + 8 * (r >> 2) + rhalf;
            __builtin_nontemporal_store(acc[r], ob + (size_t)row * HW);
        }
    }
    #undef BFRAG
}

extern "C" void kernel_launch(void* const* d_in, const int* in_sizes, int n_in,
                              void* d_out, int out_size, void* d_ws, size_t ws_size,
                              hipStream_t stream) {
    const float* act  = (const float*)d_in[0];   // (32, 512, 56, 56) f32
    const float* filt = (const float*)d_in[1];   // (1, 1, 63) f32
    float* out = (float*)d_out;                  // (32, 512, 56, 56) f32
    dim3 grid(NB * NTILE);    // 3136
    dim3 block(TPB);
    hipLaunchKernelGGL(toeplitz_mfma32_kernel, grid, block, 0, stream,
                       act, filt, out);
}